// Round 7
// baseline (169.547 us; speedup 1.0000x reference)
//
#include <hip/hip_runtime.h>
#include <cstdint>
#include <cstddef>

// Problem constants
#define NB   32    // query batch
#define NSUP 25    // support images
#define KCLS 5     // classes
#define NC   512   // input channels
#define ND   128   // dk = dv
#define NP   196   // h*w
#define JS   208   // per-support padded spatial (13*16)
#define SHIFT 8.0f // fixed logit shift (softmax-invariant overflow guard)

// attn LDS geometry (linear rows + source-side XOR swizzle, global_load_lds):
//   K: 2 tiles x 16 rows x 256B = 8192 B   (slot sc holds global col sc^(r&7))
//   V: 128 rows x 64B           = 8192 B   (slot s2 holds global col8 s2^((d>>1)&3))
//   ABUF = 16384 B, double buffer = 32768 B
#define ABUF   16384
#define VOFF   8192

#define NGRP   (NB * KCLS * 13)          // 2080 (b,kc,pt) groups
#define PACC_F ((size_t)NGRP * 2 * 2048) // partial acc floats (2 halves)
#define PSUM_F ((size_t)NGRP * 2 * 16)   // partial Ssum floats

typedef __attribute__((ext_vector_type(8))) short short8;   // 8 x bf16 (4 VGPRs)
typedef __attribute__((ext_vector_type(4))) float floatx4;  // MFMA C/D

__device__ inline short f2bf(float x) {
  union { float f; uint32_t u; } v; v.f = x;
  uint32_t r = (v.u + 0x7FFFu + ((v.u >> 16) & 1u)) >> 16;  // RNE
  return (short)(r & 0xFFFFu);
}
// single-instruction packed f32x2 -> bf16x2 (RNE, same as f2bf for non-NaN)
__device__ inline uint32_t cvtpk(float lo, float hi) {
  uint32_t r;
  asm("v_cvt_pk_bf16_f32 %0, %1, %2" : "=v"(r) : "v"(lo), "v"(hi));
  return r;
}
// async global->LDS, 16B/lane, dest = wave-uniform base + lane*16
__device__ __forceinline__ void gl_lds16(const uint16_t* g, char* l) {
  __builtin_amdgcn_global_load_lds(
      (const __attribute__((address_space(1))) uint32_t*)g,
      (__attribute__((address_space(3))) uint32_t*)l, 16, 0, 0);
}

// ---------------------------------------------------------------------------
// Kernel 0: W fp32 -> bf16. Whi[mat][d:128][c:512], mats contiguous.
// ---------------------------------------------------------------------------
__global__ __launch_bounds__(256) void wconv_kernel(
    const float* __restrict__ Wqk, const float* __restrict__ Wv,
    uint16_t* __restrict__ Whi)
{
  const int f = (blockIdx.x * 256 + (int)threadIdx.x) * 8;   // < 131072
  const float* src = (f < ND * NC) ? (Wqk + f) : (Wv + f - ND * NC);
  short8 hv;
  #pragma unroll
  for (int i = 0; i < 8; ++i) hv[i] = f2bf(src[i]);
  *(short8*)(Whi + f) = hv;
}

// ---------------------------------------------------------------------------
// Kernel 1: fused projection GEMM (structure unchanged; pk2 -> cvtpk).
//   QK: A=X(m=p), B=Wqk(n=d) -> bf16 Qt[b][p<196][d] / Kt[n][p:208][d]
//   V:  A=Wv(m=d), B=X(n=p)  -> bf16 Vt[n][d][p:208] / fp32 outVq[b][d][p]
// ---------------------------------------------------------------------------
__global__ __launch_bounds__(256) void gemm_kernel(
    const float* __restrict__ supp, const float* __restrict__ qry,
    const uint16_t* __restrict__ Whi,
    uint16_t* __restrict__ Qt, uint16_t* __restrict__ Kt,
    uint16_t* __restrict__ Vt, float* __restrict__ outVq)
{
  __shared__ uint16_t xs[16 * 520];     // 16.6 KB bf16 X tile, [p][c+pad]
  const int bx = blockIdx.x;
  const int t16 = bx % 13, img = bx / 13;
  const int tid = (int)threadIdx.x;
  const int w = tid >> 6, lane = tid & 63, ln = lane & 15, q = lane >> 4;
  const int d0 = w * 32;
  const int p0 = t16 * 16;

  const float* __restrict__ X = (img < NB)
      ? (qry  + (size_t)img * NC * NP)
      : (supp + (size_t)(img - NB) * NC * NP);

  // stage X tile as bf16: read float4 along p, write packed pairs along c
  #pragma unroll
  for (int k = 0; k < 4; ++k) {
    const int id = k * 256 + tid;
    const int cp = id >> 2;                        // c-pair: c = 2cp, 2cp+1
    const int pq = id & 3;
    int pg = p0 + pq * 4; if (pg > NP - 4) pg = NP - 4;   // clamp (pad rows masked later)
    const floatx4 fa = *(const floatx4*)(X + (2 * cp) * NP + pg);
    const floatx4 fb = *(const floatx4*)(X + (2 * cp + 1) * NP + pg);
    #pragma unroll
    for (int i = 0; i < 4; ++i)
      *((uint32_t*)xs + (pq * 4 + i) * 260 + cp) = cvtpk(fa[i], fb[i]);
  }
  __syncthreads();

  floatx4 aQ[2], aV[2];
  #pragma unroll
  for (int nt = 0; nt < 2; ++nt) {
    aQ[nt] = (floatx4){0.f, 0.f, 0.f, 0.f};
    aV[nt] = (floatx4){0.f, 0.f, 0.f, 0.f};
  }

  for (int ks = 0; ks < 16; ++ks) {
    const short8 xh = *(const short8*)&xs[ln * 520 + ks * 32 + q * 8];  // 1 ds_read_b128
    #pragma unroll
    for (int nt = 0; nt < 2; ++nt) {
      const size_t wr = (size_t)(d0 + nt * 16 + ln) * NC + ks * 32 + q * 8;
      const short8 wqh = *(const short8*)(Whi + wr);
      aQ[nt] = __builtin_amdgcn_mfma_f32_16x16x32_bf16(xh, wqh, aQ[nt], 0, 0, 0);
      const short8 wvh = *(const short8*)(Whi + (size_t)ND * NC + wr);
      aV[nt] = __builtin_amdgcn_mfma_f32_16x16x32_bf16(wvh, xh, aV[nt], 0, 0, 0);
    }
  }

  // QK: D row = p = p0+q*4+rr, col = d = d0+nt*16+ln
  if (img < NB) {
    #pragma unroll
    for (int nt = 0; nt < 2; ++nt)
      #pragma unroll
      for (int rr = 0; rr < 4; ++rr) {
        const int p = p0 + q * 4 + rr;
        if (p < NP)
          Qt[((size_t)img * NP + p) * ND + d0 + nt * 16 + ln] = (uint16_t)f2bf(aQ[nt][rr]);
      }
  } else {
    const int n = img - NB;
    #pragma unroll
    for (int nt = 0; nt < 2; ++nt)
      #pragma unroll
      for (int rr = 0; rr < 4; ++rr) {
        const int p = p0 + q * 4 + rr;              // 0..207, pads masked in attn
        Kt[((size_t)n * JS + p) * ND + d0 + nt * 16 + ln] = (uint16_t)f2bf(aQ[nt][rr]);
      }
  }
  // V: D row = d = d0+nt*16+q*4+rr, col = p = p0+ln
  const int p = p0 + ln;
  if (img < NB) {
    if (p < NP) {
      #pragma unroll
      for (int nt = 0; nt < 2; ++nt)
        #pragma unroll
        for (int rr = 0; rr < 4; ++rr)
          outVq[((size_t)img * ND + d0 + nt * 16 + q * 4 + rr) * NP + p] = aV[nt][rr];
    }
  } else {
    const int n = img - NB;
    #pragma unroll
    for (int nt = 0; nt < 2; ++nt)
      #pragma unroll
      for (int rr = 0; rr < 4; ++rr)
        Vt[((size_t)n * ND + d0 + nt * 16 + q * 4 + rr) * JS + p] = (uint16_t)f2bf(aV[nt][rr]);
  }
}

// ---------------------------------------------------------------------------
// Kernel 2: per-class masked attention. R6 skeleton (2 batches/wave, j-half
// split) with SERIAL-TIME cuts:
//  - staging via global_load_lds (16B/lane, linear LDS dest): removes the
//    per-thread decode + VGPR round-trip + ds_writes. Bank swizzle moved to
//    the SOURCE column index (m173): K slot sc^(r&7), V slot s2^((d>>1)&3),
//    same involution applied on read -> 2-way (free) LDS reads, staged
//    bytes bit-identical to R6.
//  - v_cvt_pk_bf16_f32 replaces the 9-instr pk2 (RNE-identical).
//  - s_setprio(1) around MFMA clusters (T5).
// LDS 2x16KB = 32KB. Wave roles per iteration: waves 0,1 stage K tile w;
// waves 2,3 stage V rows [0,64)/[64,128). 1 chunk (32 j) per iteration.
// grid = 13pt * 5kc * (4oct * 2half) = 520 x 256.
// ---------------------------------------------------------------------------

#define DECODE2() do {                                                         \
    _Pragma("unroll")                                                          \
    for (int t_ = 0; t_ < 2; ++t_) {                                           \
      dS[t_] = s_ctr; dJ[t_] = j_ctr;                                          \
      const int sc_ = s_ctr > 4 ? 4 : s_ctr;                                   \
      dN[t_] = (clsPack >> (6 * sc_)) & 63;                                    \
      j_ctr += 16; if (j_ctr >= JS) { j_ctr -= JS; s_ctr += 1; }               \
    }                                                                          \
  } while (0)

#define STAGE(DB) do {                                                         \
    if (w < 2) {                                                               \
      const int kb_ = (dN[w] * JS + dJ[w]) * ND;                               \
      _Pragma("unroll")                                                        \
      for (int i_ = 0; i_ < 4; ++i_)                                           \
        gl_lds16(Kt + kb_ + dKoff[i_], (DB) + w * 4096 + i_ * 1024);           \
    } else {                                                                   \
      const int vA_ = dN[0] * (ND * JS) + dJ[0];                               \
      const int vB_ = dN[1] * (ND * JS) + dJ[1];                               \
      const int vs_ = hb ? vB_ : vA_;                                          \
      const int i2b_ = (w & 1) * 4;                                            \
      _Pragma("unroll")                                                        \
      for (int k_ = 0; k_ < 4; ++k_)                                           \
        gl_lds16(Vt + vs_ + (i2b_ + k_) * (16 * JS) + vrow,                    \
                 (DB) + VOFF + (i2b_ + k_) * 1024);                            \
    }                                                                          \
  } while (0)

template <int NCHUNK, bool PART>
__global__ __launch_bounds__(256, 2) void attn_kernel(
    const uint16_t* __restrict__ Qt, const uint16_t* __restrict__ Kt,
    const uint16_t* __restrict__ Vt, const int* __restrict__ labels,
    float* __restrict__ out, float* __restrict__ pacc, float* __restrict__ psum)
{
  __shared__ __align__(16) char smem[2 * ABUF];   // 32 KB double buffer

  const int bx = blockIdx.x;
  const int pt = bx % 13;
  const int rem = bx / 13;                // PART: 40 = 5*(4*2) ; full: 20 = 5*4
  const int kc = rem % KCLS;
  const int rest = rem / KCLS;            // PART: 0..7 ; full: 0..3
  const int oct = PART ? (rest & 3) : rest;
  const int half = PART ? (rest >> 2) : 0;
  const int c0 = half * NCHUNK;           // chunk range [c0, c0+NCHUNK)
  const int b0 = oct * 8;                 // batch octet base
  const int p0 = pt * 16;
  const int tid = (int)threadIdx.x;
  const int w = tid >> 6, lane = tid & 63, ln = lane & 15, q = lane >> 4;
  const int bA = b0 + w * 2, bB = bA + 1; // this wave's two batches

  // class-support list packed in a register (6 bits/slot) via ballot
  const int myl = (lane < NSUP) ? labels[lane] : -1;
  unsigned long long m = __ballot(myl == kc);
  int clsPack = 0;
  #pragma unroll
  for (int s = 0; s < 5; ++s) {
    const int n = (m != 0ull) ? (int)__builtin_ctzll(m) : 0;
    clsPack |= n << (6 * s);
    m &= (m - 1);
  }
  clsPack = __builtin_amdgcn_readfirstlane(clsPack);   // SALU decode

  // Q B-frags (resident), per batch: B[n=p][k=d]
  short8 aqA[4], aqB[4];
  {
    int p = p0 + ln; if (p > NP - 1) p = NP - 1;
    const uint16_t* baseA = Qt + ((size_t)bA * NP + p) * ND + q * 8;
    const uint16_t* baseB = Qt + ((size_t)bB * NP + p) * ND + q * 8;
    #pragma unroll
    for (int ks = 0; ks < 4; ++ks) {
      aqA[ks] = *(const short8*)(baseA + ks * 32);
      aqB[ks] = *(const short8*)(baseB + ks * 32);
    }
  }

  floatx4 accA[8], accB[8];
  #pragma unroll
  for (int dt = 0; dt < 8; ++dt) {
    accA[dt] = (floatx4){0.f, 0.f, 0.f, 0.f};
    accB[dt] = (floatx4){0.f, 0.f, 0.f, 0.f};
  }
  float SsA = 0.f, SsB = 0.f;

  const int alo = (ln + ((q & 1) << 5)) << 2;  // bpermute byte addr (verified)
  const bool hiTile = (q >= 2);

  // ---- hoisted per-lane staging source offsets ----
  // K (waves 0,1): issue i -> row r=4i+(lane>>4), col slot sc=lane&15 holds
  // global col16 (sc ^ (r&7))
  const int rK = lane >> 4, scK = lane & 15;
  int dKoff[4];
  #pragma unroll
  for (int i = 0; i < 4; ++i) {
    const int r = 4 * i + rK;
    dKoff[i] = r * ND + ((scK ^ (r & 7)) * 8);
  }
  // V (waves 2,3): row d=16*i2+(lane>>2), slot s2=lane&3 holds global col8
  // s2p = s2 ^ ((d>>1)&3); half-select and column from the SWIZZLED index
  const int dV = lane >> 2, s2 = lane & 3;
  const int s2p = s2 ^ ((dV >> 1) & 3);     // ((16*i2+dV)>>1)&3 == (dV>>1)&3
  const int hb = s2p >> 1;                  // which 16-j half of the chunk
  const int vrow = dV * JS + (s2p & 1) * 8; // u16 units

  // ---- frag read offsets (byte, within buffer; swizzle matches source) ----
  int kfr[4];
  #pragma unroll
  for (int ks = 0; ks < 4; ++ks)
    kfr[ks] = ln * 256 + (((ks * 4 + q) ^ (ln & 7)) << 4);
  const int avb = VOFF + ln * 64 + ((q ^ ((ln >> 1) & 3)) << 4);

  // ---- decode counters (16-j tile granularity; 2 tiles per chunk) ----
  int s_ctr = (c0 * 2) / 13;
  int j_ctr = (c0 * 2 - s_ctr * 13) * 16;
  int dS[2], dJ[2], dN[2], cS[2], cJ[2];

  DECODE2();                     // chunk c0's tuples
  STAGE(smem);                   // stage chunk c0 into buf0
  __syncthreads();

  for (int it = 0; it < NCHUNK; ++it) {
    #pragma unroll
    for (int i = 0; i < 2; ++i) { cS[i] = dS[i]; cJ[i] = dJ[i]; }
    if (it < NCHUNK - 1) {
      DECODE2();                           // next chunk's tuples
      STAGE(smem + ((it + 1) & 1) * ABUF); // async loads -> other buffer
    }

    // ---- compute chunk from buffer it&1 (fragments read ONCE, 2 b's) ----
    const char* cb = smem + (it & 1) * ABUF;

    short8 av[8];
    #pragma unroll
    for (int dt = 0; dt < 8; ++dt)
      av[dt] = *(const short8*)(cb + avb + dt * 1024);

    short8 bk[2][4];
    #pragma unroll
    for (int t = 0; t < 2; ++t)
      #pragma unroll
      for (int ks = 0; ks < 4; ++ks)
        bk[t][ks] = *(const short8*)(cb + kfr[ks] + t * 4096);

    // QK as S^T (A=K m=j, B=Q n=p), exp with pad masking (verbatim, x2 b)
    floatx4 e0A, e1A, e0B, e1B;
    #pragma unroll
    for (int t = 0; t < 2; ++t) {
      floatx4 d4A = {0.f, 0.f, 0.f, 0.f};
      floatx4 d4B = {0.f, 0.f, 0.f, 0.f};
      __builtin_amdgcn_s_setprio(1);
      #pragma unroll
      for (int ks = 0; ks < 4; ++ks) {
        d4A = __builtin_amdgcn_mfma_f32_16x16x32_bf16(bk[t][ks], aqA[ks], d4A, 0, 0, 0);
        d4B = __builtin_amdgcn_mfma_f32_16x16x32_bf16(bk[t][ks], aqB[ks], d4B, 0, 0, 0);
      }
      __builtin_amdgcn_s_setprio(0);
      floatx4 evA, evB;
      #pragma unroll
      for (int r = 0; r < 4; ++r) {
        const int j = cJ[t] + q * 4 + r;
        const bool val = (cS[t] < 5 && j < NP);
        const float eA = val ? __expf(d4A[r] - SHIFT) : 0.f;
        const float eB = val ? __expf(d4B[r] - SHIFT) : 0.f;
        evA[r] = eA; SsA += eA;
        evB[r] = eB; SsB += eB;
      }
      if (t == 0) { e0A = evA; e0B = evB; } else { e1A = evA; e1B = evB; }
    }

    // D-layout -> B-operand transform (packed exchange, cvt_pk, x2 b)
    short8 bpA, bpB;
    #pragma unroll
    for (int r = 0; r < 4; ++r) {
      const uint32_t peA = cvtpk(e0A[r], e1A[r]);
      const int loA = __builtin_amdgcn_ds_bpermute(alo, (int)peA);
      const int hiA = __builtin_amdgcn_ds_bpermute(alo + 64, (int)peA);
      bpA[r]     = (short)(uint16_t)(hiTile ? (loA >> 16) : (loA & 0xFFFF));
      bpA[4 + r] = (short)(uint16_t)(hiTile ? (hiA >> 16) : (hiA & 0xFFFF));
      const uint32_t peB = cvtpk(e0B[r], e1B[r]);
      const int loB = __builtin_amdgcn_ds_bpermute(alo, (int)peB);
      const int hiB = __builtin_amdgcn_ds_bpermute(alo + 64, (int)peB);
      bpB[r]     = (short)(uint16_t)(hiTile ? (loB >> 16) : (loB & 0xFFFF));
      bpB[4 + r] = (short)(uint16_t)(hiTile ? (hiB >> 16) : (hiB & 0xFFFF));
    }

    // PV: A=V (m=d), B=P (n=p) -> D row=d col=p (av reused for both b's)
    __builtin_amdgcn_s_setprio(1);
    #pragma unroll
    for (int dt = 0; dt < 8; ++dt) {
      accA[dt] = __builtin_amdgcn_mfma_f32_16x16x32_bf16(av[dt], bpA, accA[dt], 0, 0, 0);
      accB[dt] = __builtin_amdgcn_mfma_f32_16x16x32_bf16(av[dt], bpB, accB[dt], 0, 0, 0);
    }
    __builtin_amdgcn_s_setprio(0);

    __syncthreads();   // drains global_load_lds (vmcnt) + syncs buffers
  }

  // ---- reduce Ssum across q-groups (per b) ----
  float svA = SsA;
  svA += __shfl_xor(svA, 16);
  svA += __shfl_xor(svA, 32);
  float svB = SsB;
  svB += __shfl_xor(svB, 16);
  svB += __shfl_xor(svB, 32);

  if (PART) {
    // unnormalized partials: pacc[grp][d*16+ln], psum[grp][ln]
    const size_t grpA = (((size_t)(bA * KCLS + kc)) * 13 + pt) * 2 + half;
    const size_t grpB = (((size_t)(bB * KCLS + kc)) * 13 + pt) * 2 + half;
    float* paA = pacc + grpA * 2048;
    float* paB = pacc + grpB * 2048;
    #pragma unroll
    for (int dt = 0; dt < 8; ++dt)
      #pragma unroll
      for (int rr = 0; rr < 4; ++rr) {
        paA[(dt * 16 + q * 4 + rr) * 16 + ln] = accA[dt][rr];
        paB[(dt * 16 + q * 4 + rr) * 16 + ln] = accB[dt][rr];
      }
    if (q == 0) {
      psum[grpA * 16 + ln] = svA;
      psum[grpB * 16 + ln] = svB;
    }
  } else {
    const int pp = p0 + ln;
    if (pp < NP) {
      const float invA = 1.f / svA, invB = 1.f / svB;
      float* obA = out + ((size_t)(bA * KCLS + kc) * ND + q * 4) * NP + pp;
      float* obB = out + ((size_t)(bB * KCLS + kc) * ND + q * 4) * NP + pp;
      #pragma unroll
      for (int dt = 0; dt < 8; ++dt)
        #pragma unroll
        for (int rr = 0; rr < 4; ++rr) {
          obA[(size_t)(dt * 16 + rr) * NP] = accA[dt][rr] * invA;
          obB[(size_t)(dt * 16 + rr) * NP] = accB[dt][rr] * invB;
        }
    }
  }
}

// ---------------------------------------------------------------------------
// Kernel 3: merge two halves + normalize. grid = 2080 (b*KCLS+kc, pt) x 256.
// thread (dr=tid>>4, ln=tid&15) handles 8 d-rows at col pt*16+ln.
// ---------------------------------------------------------------------------
__global__ __launch_bounds__(256) void merge_kernel(
    const float* __restrict__ pacc, const float* __restrict__ psum,
    float* __restrict__ out)
{
  const int bx = blockIdx.x;              // 2080 = 160 * 13
  const int pt = bx % 13;
  const int rem = bx / 13;                // b*KCLS + kc
  const int tid = (int)threadIdx.x;
  const int ln = tid & 15, dr = tid >> 4;
  const size_t g0 = (((size_t)rem) * 13 + pt) * 2;

  const float s = psum[g0 * 16 + ln] + psum[(g0 + 1) * 16 + ln];
  const int pp = pt * 16 + ln;
  if (pp >= NP) return;
  const float inv = 1.f / s;

  const float* pa0 = pacc + g0 * 2048;
  const float* pa1 = pacc + (g0 + 1) * 2048;
  float* ob = out + (size_t)rem * ND * NP + pp;
  #pragma unroll
  for (int i = 0; i < 8; ++i) {
    const int d = dr * 8 + i;
    ob[(size_t)d * NP] = (pa0[d * 16 + ln] + pa1[d * 16 + ln]) * inv;
  }
}

// ---------------------------------------------------------------------------
extern "C" void kernel_launch(void* const* d_in, const int* in_sizes, int n_in,
                              void* d_out, int out_size, void* d_ws, size_t ws_size,
                              hipStream_t stream) {
  const float* supp   = (const float*)d_in[0];
  const float* qry    = (const float*)d_in[1];
  const int*   labels = (const int*)d_in[2];
  const float* Wqk    = (const float*)d_in[3];
  const float* Wv     = (const float*)d_in[4];
  float* out = (float*)d_out;

  // ws layout: 4.53 MB staging + 34.3 MB partials (guarded)
  uint16_t* Whi = (uint16_t*)d_ws;                  // [2][128][512]
  uint16_t* Qt  = Whi + (size_t)2 * ND * NC;        // [32][196][128]
  uint16_t* Kt  = Qt  + (size_t)NB * NP * ND;       // [25][208][128]
  uint16_t* Vt  = Kt  + (size_t)NSUP * JS * ND;     // [25][128][208]
  float* pacc   = (float*)(Vt + (size_t)NSUP * ND * JS);
  float* psum   = pacc + PACC_F;
  const size_t need = (size_t)((char*)(psum + PSUM_F) - (char*)d_ws);
  float* outVq = out + (size_t)NB * KCLS * ND * NP; // query_v_flat region

  wconv_kernel<<<64, 256, 0, stream>>>(Wqk, Wv, Whi);
  gemm_kernel<<<741, 256, 0, stream>>>(supp, qry, Whi, Qt, Kt, Vt, outVq);
  if (ws_size >= need) {
    attn_kernel<17, true><<<520, 256, 0, stream>>>(Qt, Kt, Vt, labels, out, pacc, psum);
    merge_kernel<<<2080, 256, 0, stream>>>(pacc, psum, out);
  } else {
    attn_kernel<34, false><<<260, 256, 0, stream>>>(Qt, Kt, Vt, labels, out, nullptr, nullptr);
  }
}